// Round 14
// baseline (1465.201 us; speedup 1.0000x reference)
//
#include <hip/hip_runtime.h>

#define NN 8192
#define EE 2048
#define BB 512
#define TT 128
#define HH 128
#define G3 384
#define MAXNNZ 256
#define MAXDEG 96

typedef __attribute__((ext_vector_type(8))) _Float16 f16x8;
typedef __attribute__((ext_vector_type(4))) float f32x4;

__device__ __forceinline__ float sigm(float x){ return 1.0f/(1.0f+__expf(-x)); }
__device__ __forceinline__ float tanhfast(float x){ return 2.0f/(1.0f+__expf(-2.0f*x)) - 1.0f; }

// barrier ordering LDS only; global loads/stores stay in flight.
__device__ __forceinline__ void bar_lds(){
  __builtin_amdgcn_sched_barrier(0);
  asm volatile("s_waitcnt lgkmcnt(0)\n\ts_barrier" ::: "memory");
  __builtin_amdgcn_sched_barrier(0);
}

// ---- build per-edge nonzero index lists (Hbat is exactly binary) ----
__global__ __launch_bounds__(256)
void build_nnz(const float* __restrict__ Hb, int* __restrict__ idx, int* __restrict__ cnt){
  __shared__ int c;
  const int e = blockIdx.x;
  if (threadIdx.x == 0) c = 0;
  __syncthreads();
  const float* row = Hb + (size_t)e * NN;
  for (int n = threadIdx.x; n < NN; n += 256){
    if (row[n] != 0.0f){
      int p = atomicAdd(&c, 1);
      if (p < MAXNNZ) idx[e*MAXNNZ + p] = n;
    }
  }
  __syncthreads();
  if (threadIdx.x == 0) cnt[e] = (c < MAXNNZ ? c : MAXNNZ);
}

// ---- invert edge lists into per-node edge lists ----
__global__ __launch_bounds__(128)
void build_nodelists(const int* __restrict__ idx, const int* __restrict__ cnt,
                     int* __restrict__ ndeg, int* __restrict__ nidx){
  const int e = blockIdx.x;
  const int c = cnt[e];
  for (int k = threadIdx.x; k < c; k += 128){
    int n = idx[e*MAXNNZ + k];
    int p = atomicAdd(&ndeg[n], 1);
    if (p < MAXDEG) nidx[n*MAXDEG + p] = e;
  }
}

// ---- split (16*W) into fp16 hi/lo, row-major passthrough ----
__global__ __launch_bounds__(256)
void prep_w(const float* __restrict__ W, _Float16* __restrict__ whi,
            _Float16* __restrict__ wlo, int n){
  int i = blockIdx.x*256 + threadIdx.x;
  if (i >= n) return;
  float g = W[i] * 16.0f;
  _Float16 h = (_Float16)g;
  whi[i] = h;
  wlo[i] = (_Float16)(g - (float)h);
}

// ---- plain split X into fp16 hi/lo (no scale) ----
__global__ __launch_bounds__(256)
void prep_split(const float* __restrict__ X, _Float16* __restrict__ hi,
                _Float16* __restrict__ lo, int n){
  int i = blockIdx.x*256 + threadIdx.x;
  if (i >= n) return;
  float v = X[i];
  _Float16 h = (_Float16)v;
  hi[i] = h;
  lo[i] = (_Float16)(v - (float)h);
}

// ---- transpose + split (16*W) 128x128: wt[j,k] = 16*W[k,j] ----
__global__ __launch_bounds__(256)
void prep_wt(const float* __restrict__ W, _Float16* __restrict__ wt_hi,
             _Float16* __restrict__ wt_lo){
  int i = blockIdx.x*256 + threadIdx.x;   // 16384 total
  int k = i >> 7, j = i & 127;
  float g = W[i] * 16.0f;
  _Float16 h = (_Float16)g;
  wt_hi[j*HH + k] = h;
  wt_lo[j*HH + k] = (_Float16)(g - (float)h);
}

// ---- conv-phase MFMA GEMM on pre-split A: C[r,j] = rowscale[r]*(A@W + bias) ----
template<bool SCALE>
__global__ __launch_bounds__(256)
void mm128_mfma(const _Float16* __restrict__ Ahi, const _Float16* __restrict__ Alo,
                const _Float16* __restrict__ Bh, const _Float16* __restrict__ Bl,
                const float* __restrict__ bias, const float* __restrict__ rowscale,
                float* __restrict__ C)
{
  const int tid = threadIdx.x;
  const int w = tid >> 6, l = tid & 63;
  const int lm = l & 15, q = l >> 4;
  const int r0 = blockIdx.x * 32;
  const int n0 = w * 32;

  f32x4 acc[2][2];
  #pragma unroll
  for (int m=0;m<2;m++)
    #pragma unroll
    for (int n=0;n<2;n++) acc[m][n] = (f32x4){0.f,0.f,0.f,0.f};

  #pragma unroll 2
  for (int ks = 0; ks < 4; ++ks){
    const int kb = ks*32 + q*8;
    f16x8 ah[2], al[2];
    #pragma unroll
    for (int m=0;m<2;m++){
      const size_t ro = (size_t)(r0 + m*16 + lm)*HH + kb;
      ah[m] = *(const f16x8*)(Ahi + ro);
      al[m] = *(const f16x8*)(Alo + ro);
    }
    #pragma unroll
    for (int n=0;n<2;n++){
      const int j = n0 + n*16 + lm;
      f16x8 bh = *(const f16x8*)(Bh + (size_t)j*HH + kb);
      f16x8 bl = *(const f16x8*)(Bl + (size_t)j*HH + kb);
      #pragma unroll
      for (int m=0;m<2;m++){
        acc[m][n] = __builtin_amdgcn_mfma_f32_16x16x32_f16(ah[m], bh, acc[m][n], 0,0,0);
        acc[m][n] = __builtin_amdgcn_mfma_f32_16x16x32_f16(al[m], bh, acc[m][n], 0,0,0);
        acc[m][n] = __builtin_amdgcn_mfma_f32_16x16x32_f16(ah[m], bl, acc[m][n], 0,0,0);
      }
    }
  }
  #pragma unroll
  for (int n=0;n<2;n++){
    const int j = n0 + n*16 + lm;
    const float bv = bias[j];
    #pragma unroll
    for (int m=0;m<2;m++){
      #pragma unroll
      for (int i=0;i<4;i++){
        int r = r0 + m*16 + q*4 + i;
        float cv = acc[m][n][i]*(1.0f/16.0f) + bv;
        if (SCALE) cv *= rowscale[r];
        C[(size_t)r*HH + j] = cv;
      }
    }
  }
}

// ---- edge gather: Eb[e,:] = invDE[e] * sum_{n in edge e} Xs[n,:] ----
__global__ __launch_bounds__(128)
void edge_gather(const float* __restrict__ Xs, const int* __restrict__ idx,
                 const int* __restrict__ cnt, const float* __restrict__ invDE,
                 float* __restrict__ Eb){
  __shared__ int sidx[MAXNNZ];
  const int e = blockIdx.x, h = threadIdx.x;
  const int c = cnt[e];
  for (int k = h; k < c; k += 128) sidx[k] = idx[e*MAXNNZ + k];
  __syncthreads();
  float acc = 0.0f;
  int k = 0;
  for (; k + 4 <= c; k += 4){
    float a0 = Xs[(size_t)sidx[k+0]*HH + h];
    float a1 = Xs[(size_t)sidx[k+1]*HH + h];
    float a2 = Xs[(size_t)sidx[k+2]*HH + h];
    float a3 = Xs[(size_t)sidx[k+3]*HH + h];
    acc += (a0 + a1) + (a2 + a3);
  }
  for (; k < c; ++k) acc += Xs[(size_t)sidx[k]*HH + h];
  Eb[e*HH + h] = invDE[e] * acc;
}

// ---- node gather: v = DV2[n] * sum_{e ∋ n} Eb[e,:]; MODE1: split(relu(v)+poi), MODE2: fp32 v ----
template<int MODE>
__global__ __launch_bounds__(128)
void node_gather(const float* __restrict__ Eb, const int* __restrict__ nidx,
                 const int* __restrict__ ndeg, const float* __restrict__ DV2,
                 const float* __restrict__ poi, _Float16* __restrict__ ohi,
                 _Float16* __restrict__ olo, float* __restrict__ Xo){
  __shared__ int sidx[MAXDEG];
  const int n = blockIdx.x, h = threadIdx.x;
  int c = ndeg[n]; c = c < MAXDEG ? c : MAXDEG;
  for (int k = h; k < c; k += 128) sidx[k] = nidx[n*MAXDEG + k];
  __syncthreads();
  float acc = 0.0f;
  int k = 0;
  for (; k + 4 <= c; k += 4){
    float a0 = Eb[(size_t)sidx[k+0]*HH + h];
    float a1 = Eb[(size_t)sidx[k+1]*HH + h];
    float a2 = Eb[(size_t)sidx[k+2]*HH + h];
    float a3 = Eb[(size_t)sidx[k+3]*HH + h];
    acc += (a0 + a1) + (a2 + a3);
  }
  for (; k < c; ++k) acc += Eb[(size_t)sidx[k]*HH + h];
  float v = DV2[n] * acc;
  if (MODE == 1){
    float val = fmaxf(v, 0.0f) + poi[(size_t)n*HH + h];
    _Float16 hh = (_Float16)val;
    ohi[(size_t)n*HH + h] = hh;
    olo[(size_t)n*HH + h] = (_Float16)(val - (float)hh);
  } else {
    Xo[(size_t)n*HH + h] = v;
  }
}

// ---- gather emb rows -> fp16 hi/lo split (layer-0 A operand; residual source) ----
__global__ __launch_bounds__(256)
void gather_emb(const float* __restrict__ X, const int* __restrict__ data,
                _Float16* __restrict__ aHi, _Float16* __restrict__ aLo){
  int r = blockIdx.x*2 + (threadIdx.x >> 7);
  int h = threadIdx.x & 127;
  int n = data[r];
  float v = X[(size_t)n*HH + h];
  size_t o = (size_t)r*HH + h;
  _Float16 hh = (_Float16)v;
  aHi[o] = hh;
  aLo[o] = (_Float16)(v - (float)hh);
}

// ---- lockstep-skew pipelined 3-layer GRU:
// one block = 2 batches; 3 wave-groups (4 waves each) = 3 layers, advancing
// in 8-step chunks; group g at super-step s works on chunk c = s-g.
// All sync = ordinary block-wide barriers (uniform counts, no flags).
__global__ __launch_bounds__(768, 3)
void gru_pipe2(const float* __restrict__ WhhAll, const float* __restrict__ bhhAll,
               const _Float16* __restrict__ WhiAll, const _Float16* __restrict__ WloAll,
               const float* __restrict__ bihAll, const int* __restrict__ lens,
               const _Float16* __restrict__ a0Hi, const _Float16* __restrict__ a0Lo,
               _Float16* __restrict__ aAHi, _Float16* __restrict__ aALo,
               _Float16* __restrict__ aBHi, _Float16* __restrict__ aBLo,
               float* __restrict__ out)
{
  __shared__ _Float16 hbufs[3][2][16*HH];   // 24 KB
  __shared__ float ghT[3][2][392];          // 9.4 KB
  __shared__ float ring[3][2][8][G3];       // 73.7 KB: [grp][batch][t%8][col]

  const int tid = threadIdx.x;
  const int g = tid >> 8;            // layer group 0..2
  const int gtid = tid & 255;
  const int lane = tid & 63;
  const int lm = lane & 15, q = lane >> 4;
  const int gw = gtid >> 6;          // wave within group 0..3
  const int n0 = gw * 96;            // wave's 96-col slab
  const int b0 = blockIdx.x * 2;

  const int len0 = lens[b0], len1 = lens[b0+1];
  const int lenmax = len0;           // sorted descending
  const int nch = (lenmax + 7) >> 3;

  // Whh fragments for this group's layer: wf[6][4] = 96 VGPR
  const float* Whh = WhhAll + (size_t)g*G3*HH;
  f16x8 wf[6][4];
  #pragma unroll
  for (int j=0; j<6; ++j){
    const float* wr = Whh + (size_t)(n0 + j*16 + lm)*HH;
    #pragma unroll
    for (int ks=0; ks<4; ++ks){
      const int kb = ks*32 + q*8;
      float4 f0 = *(const float4*)(wr + kb);
      float4 f1 = *(const float4*)(wr + kb + 4);
      float fv[8] = {f0.x,f0.y,f0.z,f0.w,f1.x,f1.y,f1.z,f1.w};
      union { f16x8 v; _Float16 u[8]; } uu;
      #pragma unroll
      for (int jj=0;jj<8;jj++) uu.u[jj] = (_Float16)(fv[jj] * 16.0f);
      wf[j][ks] = uu.v;
    }
  }
  const float S = 1.0f/16.0f;

  // gate mapping: 256 threads/group = 2 batches x 128 dims
  const int gb = gtid >> 7, gd = gtid & 127;
  const float bRR = bihAll[g*G3 + gd]       + bhhAll[g*G3 + gd];
  const float bZZ = bihAll[g*G3 + 128 + gd] + bhhAll[g*G3 + 128 + gd];
  const float bi2 = bihAll[g*G3 + 256 + gd];
  const float bN  = bhhAll[g*G3 + 256 + gd];
  const int glen = gb ? len1 : len0;

  const _Float16* aInHi = (g==0) ? a0Hi : (g==1 ? aAHi : aBHi);
  const _Float16* aInLo = (g==0) ? a0Lo : (g==1 ? aALo : aBLo);
  _Float16* aOutHi = (g==0) ? aAHi : aBHi;   // g==2 unused
  _Float16* aOutLo = (g==0) ? aALo : aBLo;
  const size_t eb = ((size_t)(b0+gb)*TT)*HH + gd;

  const _Float16* WihHi = WhiAll + (size_t)g*G3*HH;
  const _Float16* WihLo = WloAll + (size_t)g*G3*HH;

  {   // zero all h buffers
    unsigned int* z = (unsigned int*)&hbufs[0][0][0];
    #pragma unroll 1
    for (int i = tid; i < 3*2*16*HH/2; i += 768) z[i] = 0u;
  }
  __syncthreads();

  float hp = 0.f, fo = 0.f;
  int cur = 0;
  const int ntot = nch + 2;

  #pragma unroll 1
  for (int s = 0; s < ntot; ++s){
    const int c = s - g;
    const bool act = (c >= 0) && (c < nch);

    // ---- gx phase: chunk c (8 t-rows x 384 cols, per batch) -> LDS ring ----
    if (act){
      #pragma unroll 1
      for (int bb = 0; bb < 2; ++bb){
        f32x4 acc[6];
        #pragma unroll
        for (int j=0;j<6;j++) acc[j] = (f32x4){0.f,0.f,0.f,0.f};
        #pragma unroll
        for (int ks = 0; ks < 4; ++ks){
          const int kb = ks*32 + q*8;
          int row = c*8 + lm; if (row > TT-1) row = TT-1;   // rows 8..15 discarded
          const size_t ro = ((size_t)(b0+bb)*TT + row)*HH + kb;
          f16x8 ah = *(const f16x8*)(aInHi + ro);
          f16x8 al = *(const f16x8*)(aInLo + ro);
          #pragma unroll
          for (int j=0;j<6;j++){
            const size_t wb = (size_t)(n0 + j*16 + lm)*HH + kb;
            f16x8 bh = *(const f16x8*)(WihHi + wb);
            f16x8 bl = *(const f16x8*)(WihLo + wb);
            acc[j] = __builtin_amdgcn_mfma_f32_16x16x32_f16(ah, bh, acc[j], 0,0,0);
            acc[j] = __builtin_amdgcn_mfma_f32_16x16x32_f16(al, bh, acc[j], 0,0,0);
            acc[j] = __builtin_amdgcn_mfma_f32_16x16x32_f16(ah, bl, acc[j], 0,0,0);
          }
        }
        if (q < 2){   // rows 0..7 = valid chunk rows
          #pragma unroll
          for (int j=0;j<6;j++){
            #pragma unroll
            for (int i=0;i<4;i++)
              ring[g][bb][q*4+i][n0 + j*16 + lm] = acc[j][i]*S;
          }
        }
      }
    }
    bar_lds();   // ring visible to group's phase-B threads

    // ---- 8 scan steps ----
    #pragma unroll 1
    for (int s8 = 0; s8 < 8; ++s8){
      const int t = c*8 + s8;
      f16x8 av[4];
      float xv0=0.f, xv1=0.f, xv2=0.f, xef=0.f;
      if (act){
        #pragma unroll
        for (int ks=0; ks<4; ++ks){
          int off = (lm*256 + ks*64 + q*16) ^ ((lm & 7) << 4);
          av[ks] = *(const f16x8*)((const char*)&hbufs[g][cur][0] + off);
        }
        const float* rp = &ring[g][gb][s8][0];
        xv0 = rp[gd]; xv1 = rp[128+gd]; xv2 = rp[256+gd];
        if (g < 2){
          int tq = t < TT-1 ? t : TT-1;
          size_t o = eb + (size_t)tq*HH;
          xef = (float)a0Hi[o] + (float)a0Lo[o];
        }
      }
      if (act){
        #pragma unroll
        for (int pass=0; pass<2; ++pass){
          f32x4 aA_ = (f32x4){0.f,0.f,0.f,0.f}, aB_ = aA_, aC_ = aA_;
          #pragma unroll
          for (int ks=0; ks<4; ++ks){
            aA_ = __builtin_amdgcn_mfma_f32_16x16x32_f16(av[ks], wf[pass*3+0][ks], aA_, 0,0,0);
            aB_ = __builtin_amdgcn_mfma_f32_16x16x32_f16(av[ks], wf[pass*3+1][ks], aB_, 0,0,0);
            aC_ = __builtin_amdgcn_mfma_f32_16x16x32_f16(av[ks], wf[pass*3+2][ks], aC_, 0,0,0);
          }
          if (q == 0){   // rows 0,1 = batches 0,1
            const int c0 = n0 + pass*48 + lm;
            ghT[g][0][c0]      = aA_[0];  ghT[g][1][c0]      = aA_[1];
            ghT[g][0][c0+16]   = aB_[0];  ghT[g][1][c0+16]   = aB_[1];
            ghT[g][0][c0+32]   = aC_[0];  ghT[g][1][c0+32]   = aC_[1];
          }
        }
      }
      bar_lds();

      if (act){
        float gr = ghT[g][gb][gd], gz = ghT[g][gb][128+gd], gn = ghT[g][gb][256+gd];
        float r = sigm(xv0 + gr*S + bRR);
        float z = sigm(xv1 + gz*S + bZZ);
        float n = tanhfast(xv2 + bi2 + r*(gn*S + bN));
        float hnew = (1.0f - z)*n + z*hp;
        hp = hnew;
        int off = (gb*256 + gd*2) ^ (gb << 4);
        *(_Float16*)((char*)&hbufs[g][cur^1][0] + off) = (_Float16)hnew;
        if (g < 2){
          if (t < TT){
            float a = xef + fmaxf(hnew, 0.0f);
            _Float16 ah = (_Float16)a;
            aOutHi[eb + (size_t)t*HH] = ah;
            aOutLo[eb + (size_t)t*HH] = (_Float16)(a - (float)ah);
          }
        } else {
          if (t == glen - 1) fo = tanhfast(hnew);
        }
      }
      bar_lds();
      cur ^= 1;
    }

    // super-step boundary: drain aOut stores, then full barrier
    asm volatile("s_waitcnt vmcnt(0)" ::: "memory");
    __syncthreads();
  }

  if (g == 2)
    out[(size_t)(b0+gb)*HH + gd] = fo;
}

extern "C" void kernel_launch(void* const* d_in, const int* in_sizes, int n_in,
                              void* d_out, int out_size, void* d_ws, size_t ws_size,
                              hipStream_t stream)
{
  const float* Hb    = (const float*)d_in[0];
  const float* DV2   = (const float*)d_in[1];
  const float* invDE = (const float*)d_in[2];
  const int*   data  = (const int*)d_in[3];
  const int*   dlen  = (const int*)d_in[4];
  const float* poi   = (const float*)d_in[5];
  const float* w1    = (const float*)d_in[6];
  const float* b1    = (const float*)d_in[7];
  const float* w2    = (const float*)d_in[8];
  const float* b2    = (const float*)d_in[9];
  const float* Wih   = (const float*)d_in[10];
  const float* Whh   = (const float*)d_in[11];
  const float* bih   = (const float*)d_in[12];
  const float* bhh   = (const float*)d_in[13];
  float* out = (float*)d_out;

  float* ws   = (float*)d_ws;
  float* x1s  = ws;                          // N*H f32
  float* x3s  = x1s + (size_t)NN*HH;         // N*H f32
  float* x4   = x3s + (size_t)NN*HH;         // N*H f32
  float* ebuf = x4  + (size_t)NN*HH;         // E*H f32
  _Float16* a0Hi = (_Float16*)(ebuf + (size_t)EE*HH);   // B*T*H each
  _Float16* a0Lo = a0Hi + (size_t)BB*TT*HH;
  _Float16* aAHi = a0Lo + (size_t)BB*TT*HH;
  _Float16* aALo = aAHi + (size_t)BB*TT*HH;
  _Float16* aBHi = aALo + (size_t)BB*TT*HH;
  _Float16* aBLo = aBHi + (size_t)BB*TT*HH;
  _Float16* x2hi = aBLo + (size_t)BB*TT*HH;  // N*H
  _Float16* x2lo = x2hi + (size_t)NN*HH;
  _Float16* pHi  = x2lo + (size_t)NN*HH;     // N*H
  _Float16* pLo  = pHi + (size_t)NN*HH;
  _Float16* Whi  = pLo + (size_t)NN*HH;      // 3*384*128
  _Float16* Wlo  = Whi + (size_t)3*G3*HH;
  _Float16* w1th = Wlo + (size_t)3*G3*HH;    // 128*128 each
  _Float16* w1tl = w1th + (size_t)HH*HH;
  _Float16* w2th = w1tl + (size_t)HH*HH;
  _Float16* w2tl = w2th + (size_t)HH*HH;
  int* idx  = (int*)(w2tl + (size_t)HH*HH);  // E*MAXNNZ
  int* cnt  = idx + (size_t)EE*MAXNNZ;       // E
  int* ndeg = cnt + EE;                      // N
  int* nidx = ndeg + NN;                     // N*MAXDEG

  // ---- prep ----
  hipMemsetAsync(ndeg, 0, NN*sizeof(int), stream);
  build_nnz<<<EE, 256, 0, stream>>>(Hb, idx, cnt);
  build_nodelists<<<EE, 128, 0, stream>>>(idx, cnt, ndeg, nidx);
  prep_w<<<(3*G3*HH + 255)/256, 256, 0, stream>>>(Wih, Whi, Wlo, 3*G3*HH);
  prep_wt<<<HH*HH/256, 256, 0, stream>>>(w1, w1th, w1tl);
  prep_wt<<<HH*HH/256, 256, 0, stream>>>(w2, w2th, w2tl);
  prep_split<<<NN*HH/256, 256, 0, stream>>>(poi, pHi, pLo, NN*HH);

  // ---- hypergraph conv phase ----
  mm128_mfma<true><<<NN/32, 256, 0, stream>>>(pHi, pLo, w1th, w1tl, b1, DV2, x1s);
  edge_gather<<<EE, 128, 0, stream>>>(x1s, idx, cnt, invDE, ebuf);
  node_gather<1><<<NN, 128, 0, stream>>>(ebuf, nidx, ndeg, DV2, poi, x2hi, x2lo, (float*)nullptr);
  mm128_mfma<true><<<NN/32, 256, 0, stream>>>(x2hi, x2lo, w2th, w2tl, b2, DV2, x3s);
  edge_gather<<<EE, 128, 0, stream>>>(x3s, idx, cnt, invDE, ebuf);
  node_gather<2><<<NN, 128, 0, stream>>>(ebuf, nidx, ndeg, DV2, (const float*)nullptr,
                                         (_Float16*)nullptr, (_Float16*)nullptr, x4);
  gather_emb<<<BB*TT/2, 256, 0, stream>>>(x4, data, a0Hi, a0Lo);

  // ---- lockstep-skew pipelined 3-layer GRU stack ----
  gru_pipe2<<<BB/2, 768, 0, stream>>>(Whh, bhh, Whi, Wlo, bih, dlen,
                                      a0Hi, a0Lo, aAHi, aALo, aBHi, aBLo, out);
}

// Round 15
// 554.384 us; speedup vs baseline: 2.6429x; 2.6429x over previous
//
#include <hip/hip_runtime.h>

#define NN 8192
#define EE 2048
#define BB 512
#define TT 128
#define HH 128
#define G3 384
#define MAXNNZ 256
#define MAXDEG 96

typedef __attribute__((ext_vector_type(8))) _Float16 f16x8;
typedef __attribute__((ext_vector_type(4))) float f32x4;

__device__ __forceinline__ float sigm(float x){ return 1.0f/(1.0f+__expf(-x)); }
__device__ __forceinline__ float tanhfast(float x){ return 2.0f/(1.0f+__expf(-2.0f*x)) - 1.0f; }

// barrier ordering LDS only; global loads/stores stay in flight.
__device__ __forceinline__ void bar_lds(){
  __builtin_amdgcn_sched_barrier(0);
  asm volatile("s_waitcnt lgkmcnt(0)\n\ts_barrier" ::: "memory");
  __builtin_amdgcn_sched_barrier(0);
}

// ---- build per-edge nonzero index lists (Hbat is exactly binary) ----
__global__ __launch_bounds__(256)
void build_nnz(const float* __restrict__ Hb, int* __restrict__ idx, int* __restrict__ cnt){
  __shared__ int c;
  const int e = blockIdx.x;
  if (threadIdx.x == 0) c = 0;
  __syncthreads();
  const float* row = Hb + (size_t)e * NN;
  for (int n = threadIdx.x; n < NN; n += 256){
    if (row[n] != 0.0f){
      int p = atomicAdd(&c, 1);
      if (p < MAXNNZ) idx[e*MAXNNZ + p] = n;
    }
  }
  __syncthreads();
  if (threadIdx.x == 0) cnt[e] = (c < MAXNNZ ? c : MAXNNZ);
}

// ---- invert edge lists into per-node edge lists ----
__global__ __launch_bounds__(128)
void build_nodelists(const int* __restrict__ idx, const int* __restrict__ cnt,
                     int* __restrict__ ndeg, int* __restrict__ nidx){
  const int e = blockIdx.x;
  const int c = cnt[e];
  for (int k = threadIdx.x; k < c; k += 128){
    int n = idx[e*MAXNNZ + k];
    int p = atomicAdd(&ndeg[n], 1);
    if (p < MAXDEG) nidx[n*MAXDEG + p] = e;
  }
}

// ---- split (16*W) into fp16 hi/lo, row-major passthrough ----
__global__ __launch_bounds__(256)
void prep_w(const float* __restrict__ W, _Float16* __restrict__ whi,
            _Float16* __restrict__ wlo, int n){
  int i = blockIdx.x*256 + threadIdx.x;
  if (i >= n) return;
  float g = W[i] * 16.0f;
  _Float16 h = (_Float16)g;
  whi[i] = h;
  wlo[i] = (_Float16)(g - (float)h);
}

// ---- plain split X into fp16 hi/lo (no scale) ----
__global__ __launch_bounds__(256)
void prep_split(const float* __restrict__ X, _Float16* __restrict__ hi,
                _Float16* __restrict__ lo, int n){
  int i = blockIdx.x*256 + threadIdx.x;
  if (i >= n) return;
  float v = X[i];
  _Float16 h = (_Float16)v;
  hi[i] = h;
  lo[i] = (_Float16)(v - (float)h);
}

// ---- transpose + split (16*W) 128x128: wt[j,k] = 16*W[k,j] ----
__global__ __launch_bounds__(256)
void prep_wt(const float* __restrict__ W, _Float16* __restrict__ wt_hi,
             _Float16* __restrict__ wt_lo){
  int i = blockIdx.x*256 + threadIdx.x;   // 16384 total
  int k = i >> 7, j = i & 127;
  float g = W[i] * 16.0f;
  _Float16 h = (_Float16)g;
  wt_hi[j*HH + k] = h;
  wt_lo[j*HH + k] = (_Float16)(g - (float)h);
}

// ---- conv-phase MFMA GEMM on pre-split A: C[r,j] = rowscale[r]*(A@W + bias) ----
template<bool SCALE>
__global__ __launch_bounds__(256)
void mm128_mfma(const _Float16* __restrict__ Ahi, const _Float16* __restrict__ Alo,
                const _Float16* __restrict__ Bh, const _Float16* __restrict__ Bl,
                const float* __restrict__ bias, const float* __restrict__ rowscale,
                float* __restrict__ C)
{
  const int tid = threadIdx.x;
  const int w = tid >> 6, l = tid & 63;
  const int lm = l & 15, q = l >> 4;
  const int r0 = blockIdx.x * 32;
  const int n0 = w * 32;

  f32x4 acc[2][2];
  #pragma unroll
  for (int m=0;m<2;m++)
    #pragma unroll
    for (int n=0;n<2;n++) acc[m][n] = (f32x4){0.f,0.f,0.f,0.f};

  #pragma unroll 2
  for (int ks = 0; ks < 4; ++ks){
    const int kb = ks*32 + q*8;
    f16x8 ah[2], al[2];
    #pragma unroll
    for (int m=0;m<2;m++){
      const size_t ro = (size_t)(r0 + m*16 + lm)*HH + kb;
      ah[m] = *(const f16x8*)(Ahi + ro);
      al[m] = *(const f16x8*)(Alo + ro);
    }
    #pragma unroll
    for (int n=0;n<2;n++){
      const int j = n0 + n*16 + lm;
      f16x8 bh = *(const f16x8*)(Bh + (size_t)j*HH + kb);
      f16x8 bl = *(const f16x8*)(Bl + (size_t)j*HH + kb);
      #pragma unroll
      for (int m=0;m<2;m++){
        acc[m][n] = __builtin_amdgcn_mfma_f32_16x16x32_f16(ah[m], bh, acc[m][n], 0,0,0);
        acc[m][n] = __builtin_amdgcn_mfma_f32_16x16x32_f16(al[m], bh, acc[m][n], 0,0,0);
        acc[m][n] = __builtin_amdgcn_mfma_f32_16x16x32_f16(ah[m], bl, acc[m][n], 0,0,0);
      }
    }
  }
  #pragma unroll
  for (int n=0;n<2;n++){
    const int j = n0 + n*16 + lm;
    const float bv = bias[j];
    #pragma unroll
    for (int m=0;m<2;m++){
      #pragma unroll
      for (int i=0;i<4;i++){
        int r = r0 + m*16 + q*4 + i;
        float cv = acc[m][n][i]*(1.0f/16.0f) + bv;
        if (SCALE) cv *= rowscale[r];
        C[(size_t)r*HH + j] = cv;
      }
    }
  }
}

// ---- edge gather: Eb[e,:] = invDE[e] * sum_{n in edge e} Xs[n,:] ----
__global__ __launch_bounds__(128)
void edge_gather(const float* __restrict__ Xs, const int* __restrict__ idx,
                 const int* __restrict__ cnt, const float* __restrict__ invDE,
                 float* __restrict__ Eb){
  __shared__ int sidx[MAXNNZ];
  const int e = blockIdx.x, h = threadIdx.x;
  const int c = cnt[e];
  for (int k = h; k < c; k += 128) sidx[k] = idx[e*MAXNNZ + k];
  __syncthreads();
  float acc = 0.0f;
  int k = 0;
  for (; k + 4 <= c; k += 4){
    float a0 = Xs[(size_t)sidx[k+0]*HH + h];
    float a1 = Xs[(size_t)sidx[k+1]*HH + h];
    float a2 = Xs[(size_t)sidx[k+2]*HH + h];
    float a3 = Xs[(size_t)sidx[k+3]*HH + h];
    acc += (a0 + a1) + (a2 + a3);
  }
  for (; k < c; ++k) acc += Xs[(size_t)sidx[k]*HH + h];
  Eb[e*HH + h] = invDE[e] * acc;
}

// ---- node gather: v = DV2[n] * sum_{e ∋ n} Eb[e,:]; MODE1: split(relu(v)+poi), MODE2: fp32 v ----
template<int MODE>
__global__ __launch_bounds__(128)
void node_gather(const float* __restrict__ Eb, const int* __restrict__ nidx,
                 const int* __restrict__ ndeg, const float* __restrict__ DV2,
                 const float* __restrict__ poi, _Float16* __restrict__ ohi,
                 _Float16* __restrict__ olo, float* __restrict__ Xo){
  __shared__ int sidx[MAXDEG];
  const int n = blockIdx.x, h = threadIdx.x;
  int c = ndeg[n]; c = c < MAXDEG ? c : MAXDEG;
  for (int k = h; k < c; k += 128) sidx[k] = nidx[n*MAXDEG + k];
  __syncthreads();
  float acc = 0.0f;
  int k = 0;
  for (; k + 4 <= c; k += 4){
    float a0 = Eb[(size_t)sidx[k+0]*HH + h];
    float a1 = Eb[(size_t)sidx[k+1]*HH + h];
    float a2 = Eb[(size_t)sidx[k+2]*HH + h];
    float a3 = Eb[(size_t)sidx[k+3]*HH + h];
    acc += (a0 + a1) + (a2 + a3);
  }
  for (; k < c; ++k) acc += Eb[(size_t)sidx[k]*HH + h];
  float v = DV2[n] * acc;
  if (MODE == 1){
    float val = fmaxf(v, 0.0f) + poi[(size_t)n*HH + h];
    _Float16 hh = (_Float16)val;
    ohi[(size_t)n*HH + h] = hh;
    olo[(size_t)n*HH + h] = (_Float16)(val - (float)hh);
  } else {
    Xo[(size_t)n*HH + h] = v;
  }
}

// ---- gather emb rows -> fp16 hi/lo split (layer-0 A operand; residual source) ----
__global__ __launch_bounds__(256)
void gather_emb(const float* __restrict__ X, const int* __restrict__ data,
                _Float16* __restrict__ aHi, _Float16* __restrict__ aLo){
  int r = blockIdx.x*2 + (threadIdx.x >> 7);
  int h = threadIdx.x & 127;
  int n = data[r];
  float v = X[(size_t)n*HH + h];
  size_t o = (size_t)r*HH + h;
  _Float16 hh = (_Float16)v;
  aHi[o] = hh;
  aLo[o] = (_Float16)(v - (float)hh);
}

// ---- fused 3-layer GRU stack (r11 structure + XCD swizzle + ILP tweaks) ----
__global__ __launch_bounds__(512, 1)
void gru_fused(const float* __restrict__ WhhAll, const float* __restrict__ bhhAll,
               const _Float16* __restrict__ WhiAll, const _Float16* __restrict__ WloAll,
               const float* __restrict__ bihAll, const int* __restrict__ lens,
               const float* __restrict__ emb_unused, _Float16* __restrict__ a0Hi,
               _Float16* __restrict__ a0Lo, _Float16* __restrict__ aAHi,
               _Float16* __restrict__ aALo, _Float16* __restrict__ aBHi,
               _Float16* __restrict__ aBLo, float* __restrict__ gxb,
               float* __restrict__ out)
{
  __shared__ _Float16 hbuf[2][16*HH];   // 8 KB; rows 2..15 stay zero
  __shared__ float ghT[2][392];
  const int tid = threadIdx.x;
  const int w = tid >> 6, lane = tid & 63;
  const int lm = lane & 15, q = lane >> 4;
  // XCD-aware swizzle: same-XCD blocks (p%8 equal) -> consecutive batch pairs
  const int p = blockIdx.x;
  const int swz = ((p & 7) << 5) | (p >> 3);    // 256 = 8 XCDs x 32
  const int b0 = swz * 2;
  const int n0 = w * 48;                // wave's 48-col slab (8 waves = 384)

  const int len0 = lens[b0], len1 = lens[b0+1];
  const int lenmax = len0;              // sorted descending
  const int ntl[2] = {(len0+15)>>4, (len1+15)>>4};

  // phase-B mapping (tid < 256): batch gb, dim gd
  const int gb = (tid < 256) ? (tid >> 7) : 0;
  const int gd = tid & 127;
  const float* gxrow = gxb + (size_t)(b0+gb)*TT*G3;
  _Float16* ahrow; _Float16* alrow;
  const int glen = gb ? len1 : len0;
  const size_t eb = ((size_t)(b0+gb)*TT)*HH + gd;

  #pragma unroll 1
  for (int l = 0; l < 3; ++l){
    const bool fin = (l == 2);
    const _Float16* Whi = WhiAll + (size_t)l*G3*HH;
    const _Float16* Wlo = WloAll + (size_t)l*G3*HH;
    const float* bih = bihAll + l*G3;
    const float* Whh = WhhAll + (size_t)l*G3*HH;
    const float* bhh = bhhAll + l*G3;
    const _Float16* aInHi = (l==0) ? a0Hi : (l==1 ? aAHi : aBHi);
    const _Float16* aInLo = (l==0) ? a0Lo : (l==1 ? aALo : aBLo);
    _Float16* aOutHi = (l==0) ? aAHi : aBHi;
    _Float16* aOutLo = (l==0) ? aALo : aBLo;

    // ---- gx phase: gx[b][t][g] = A @ Wih^T + bih for this block's rows ----
    #pragma unroll 1
    for (int bb = 0; bb < 2; ++bb){
      const int ntb = ntl[bb];
      #pragma unroll 2
      for (int rt = 0; rt < ntb; ++rt){
        f32x4 acc0 = (f32x4){0.f,0.f,0.f,0.f}, acc1 = acc0, acc2 = acc0;
        #pragma unroll
        for (int ks = 0; ks < 4; ++ks){
          const int kb = ks*32 + q*8;
          const size_t ro = ((size_t)(b0+bb)*TT + rt*16 + lm)*HH + kb;
          f16x8 ah = *(const f16x8*)(aInHi + ro);
          f16x8 al = *(const f16x8*)(aInLo + ro);
          {
            const int g = n0 + lm;
            f16x8 bh = *(const f16x8*)(Whi + (size_t)g*HH + kb);
            f16x8 bl = *(const f16x8*)(Wlo + (size_t)g*HH + kb);
            acc0 = __builtin_amdgcn_mfma_f32_16x16x32_f16(ah, bh, acc0, 0,0,0);
            acc0 = __builtin_amdgcn_mfma_f32_16x16x32_f16(al, bh, acc0, 0,0,0);
            acc0 = __builtin_amdgcn_mfma_f32_16x16x32_f16(ah, bl, acc0, 0,0,0);
          }
          {
            const int g = n0 + 16 + lm;
            f16x8 bh = *(const f16x8*)(Whi + (size_t)g*HH + kb);
            f16x8 bl = *(const f16x8*)(Wlo + (size_t)g*HH + kb);
            acc1 = __builtin_amdgcn_mfma_f32_16x16x32_f16(ah, bh, acc1, 0,0,0);
            acc1 = __builtin_amdgcn_mfma_f32_16x16x32_f16(al, bh, acc1, 0,0,0);
            acc1 = __builtin_amdgcn_mfma_f32_16x16x32_f16(ah, bl, acc1, 0,0,0);
          }
          {
            const int g = n0 + 32 + lm;
            f16x8 bh = *(const f16x8*)(Whi + (size_t)g*HH + kb);
            f16x8 bl = *(const f16x8*)(Wlo + (size_t)g*HH + kb);
            acc2 = __builtin_amdgcn_mfma_f32_16x16x32_f16(ah, bh, acc2, 0,0,0);
            acc2 = __builtin_amdgcn_mfma_f32_16x16x32_f16(al, bh, acc2, 0,0,0);
            acc2 = __builtin_amdgcn_mfma_f32_16x16x32_f16(ah, bl, acc2, 0,0,0);
          }
        }
        float* gout = gxb + ((size_t)(b0+bb)*TT + rt*16)*G3;
        #pragma unroll
        for (int i=0;i<4;i++){
          const int t = q*4 + i;
          gout[(size_t)t*G3 + n0 + lm]      = acc0[i]*(1.0f/16.0f) + bih[n0 + lm];
          gout[(size_t)t*G3 + n0 + 16 + lm] = acc1[i]*(1.0f/16.0f) + bih[n0 + 16 + lm];
          gout[(size_t)t*G3 + n0 + 32 + lm] = acc2[i]*(1.0f/16.0f) + bih[n0 + 32 + lm];
        }
      }
    }

    // ---- load Whh fragments for scan (wave w: cols n0 + {0,16,32} + lm) ----
    f16x8 wf[3][4];
    #pragma unroll
    for (int n=0; n<3; ++n){
      const int col = n0 + n*16 + lm;
      const float* wr = Whh + (size_t)col*HH;
      #pragma unroll
      for (int ks=0; ks<4; ++ks){
        const int kb = ks*32 + q*8;
        float4 f0 = *(const float4*)(wr + kb);
        float4 f1 = *(const float4*)(wr + kb + 4);
        float fv[8] = {f0.x,f0.y,f0.z,f0.w,f1.x,f1.y,f1.z,f1.w};
        union { f16x8 v; _Float16 u[8]; } uu;
        #pragma unroll
        for (int j=0;j<8;j++) uu.u[j] = (_Float16)(fv[j] * 16.0f);
        wf[n][ks] = uu.v;
      }
    }
    const float S = 1.0f/16.0f;
    const float bR = bhh[gd], bZ = bhh[HH+gd], bN = bhh[2*HH+gd];
    ahrow = aOutHi + eb;
    alrow = aOutLo + eb;

    {   // zero both h buffers
      unsigned int* z = (unsigned int*)&hbuf[0][0];
      #pragma unroll 1
      for (int i = tid; i < 2*16*HH/2; i += 512) z[i] = 0u;
    }
    __syncthreads();   // drains gx stores (vmcnt 0) + orders hbuf zero

    // prefetch t = 0
    float xv0=0.f, xv1=0.f, xv2=0.f, xe=0.f, hp=0.f, fo=0.f;
    if (tid < 256){
      xv0 = gxrow[gd]; xv1 = gxrow[128+gd]; xv2 = gxrow[256+gd];
      if (!fin) xe = (float)a0Hi[eb] + (float)a0Lo[eb];
    }

    int cur = 0;
    #pragma unroll 1
    for (int t = 0; t < lenmax; ++t){
      // phase A: MFMA on all 8 waves
      f16x8 av[4];
      #pragma unroll
      for (int ks=0; ks<4; ++ks){
        int off = (lm*256 + ks*64 + q*16) ^ ((lm & 7) << 4);
        av[ks] = *(const f16x8*)((const char*)&hbuf[cur][0] + off);
      }
      // prefetch t+1 (in flight across lgkm-only barriers)
      float xn0=0.f, xn1=0.f, xn2=0.f, xen=0.f;
      if (tid < 256){
        int tp = (t+1 < lenmax) ? t+1 : t;
        const float* bgx = gxrow + (size_t)tp*G3;
        xn0 = bgx[gd]; xn1 = bgx[128+gd]; xn2 = bgx[256+gd];
        if (!fin) xen = (float)a0Hi[eb + (size_t)tp*HH] + (float)a0Lo[eb + (size_t)tp*HH];
      }
      // 6 independent chains of depth 2, then pairwise add (shorter dep chain)
      f32x4 a0a = (f32x4){0.f,0.f,0.f,0.f}, a1a = a0a, a2a = a0a;
      f32x4 a0b = a0a, a1b = a0a, a2b = a0a;
      a0a = __builtin_amdgcn_mfma_f32_16x16x32_f16(av[0], wf[0][0], a0a, 0,0,0);
      a1a = __builtin_amdgcn_mfma_f32_16x16x32_f16(av[0], wf[1][0], a1a, 0,0,0);
      a2a = __builtin_amdgcn_mfma_f32_16x16x32_f16(av[0], wf[2][0], a2a, 0,0,0);
      a0b = __builtin_amdgcn_mfma_f32_16x16x32_f16(av[2], wf[0][2], a0b, 0,0,0);
      a1b = __builtin_amdgcn_mfma_f32_16x16x32_f16(av[2], wf[1][2], a1b, 0,0,0);
      a2b = __builtin_amdgcn_mfma_f32_16x16x32_f16(av[2], wf[2][2], a2b, 0,0,0);
      a0a = __builtin_amdgcn_mfma_f32_16x16x32_f16(av[1], wf[0][1], a0a, 0,0,0);
      a1a = __builtin_amdgcn_mfma_f32_16x16x32_f16(av[1], wf[1][1], a1a, 0,0,0);
      a2a = __builtin_amdgcn_mfma_f32_16x16x32_f16(av[1], wf[2][1], a2a, 0,0,0);
      a0b = __builtin_amdgcn_mfma_f32_16x16x32_f16(av[3], wf[0][3], a0b, 0,0,0);
      a1b = __builtin_amdgcn_mfma_f32_16x16x32_f16(av[3], wf[1][3], a1b, 0,0,0);
      a2b = __builtin_amdgcn_mfma_f32_16x16x32_f16(av[3], wf[2][3], a2b, 0,0,0);
      if (q == 0){   // rows 0,1 = batches 0,1
        const int c0 = n0 + lm;
        ghT[0][c0]      = a0a[0] + a0b[0];  ghT[1][c0]      = a0a[1] + a0b[1];
        ghT[0][c0+16]   = a1a[0] + a1b[0];  ghT[1][c0+16]   = a1a[1] + a1b[1];
        ghT[0][c0+32]   = a2a[0] + a2b[0];  ghT[1][c0+32]   = a2a[1] + a2b[1];
      }
      bar_lds();

      // phase B: one gate-triple per thread (tid < 256)
      if (tid < 256){
        float gr = ghT[gb][gd], gz = ghT[gb][128+gd], gn = ghT[gb][256+gd];
        float r = sigm(xv0 + gr*S + bR);
        float z = sigm(xv1 + gz*S + bZ);
        float n = tanhfast(xv2 + r*(gn*S + bN));
        float hnew = (1.0f - z)*n + z*hp;
        hp = hnew;
        int off = (gb*256 + gd*2) ^ (gb << 4);
        *(_Float16*)((char*)&hbuf[cur^1][0] + off) = (_Float16)hnew;
        if (!fin){
          float a = xe + fmaxf(hnew, 0.0f);
          _Float16 ah = (_Float16)a;
          ahrow[(size_t)t*HH] = ah;
          alrow[(size_t)t*HH] = (_Float16)(a - (float)ah);
        } else {
          if (t == glen - 1) fo = tanhfast(hnew);
        }
      }
      xv0 = xn0; xv1 = xn1; xv2 = xn2; xe = xen;
      bar_lds();
      cur ^= 1;
    }

    if (fin){
      if (tid < 256)
        out[(size_t)(b0+gb)*HH + gd] = fo;
    } else {
      __syncthreads();   // drain aOut stores before next layer reads them
    }
  }
}

extern "C" void kernel_launch(void* const* d_in, const int* in_sizes, int n_in,
                              void* d_out, int out_size, void* d_ws, size_t ws_size,
                              hipStream_t stream)
{
  const float* Hb    = (const float*)d_in[0];
  const float* DV2   = (const float*)d_in[1];
  const float* invDE = (const float*)d_in[2];
  const int*   data  = (const int*)d_in[3];
  const int*   dlen  = (const int*)d_in[4];
  const float* poi   = (const float*)d_in[5];
  const float* w1    = (const float*)d_in[6];
  const float* b1    = (const float*)d_in[7];
  const float* w2    = (const float*)d_in[8];
  const float* b2    = (const float*)d_in[9];
  const float* Wih   = (const float*)d_in[10];
  const float* Whh   = (const float*)d_in[11];
  const float* bih   = (const float*)d_in[12];
  const float* bhh   = (const float*)d_in[13];
  float* out = (float*)d_out;

  float* ws   = (float*)d_ws;
  float* x1s  = ws;                          // N*H f32
  float* x3s  = x1s + (size_t)NN*HH;         // N*H f32
  float* x4   = x3s + (size_t)NN*HH;         // N*H f32
  float* ebuf = x4  + (size_t)NN*HH;         // E*H f32
  float* gx   = ebuf + (size_t)EE*HH;        // B*T*3H f32
  _Float16* a0Hi = (_Float16*)(gx + (size_t)BB*TT*G3);  // B*T*H each
  _Float16* a0Lo = a0Hi + (size_t)BB*TT*HH;
  _Float16* aAHi = a0Lo + (size_t)BB*TT*HH;
  _Float16* aALo = aAHi + (size_t)BB*TT*HH;
  _Float16* aBHi = aALo + (size_t)BB*TT*HH;
  _Float16* aBLo = aBHi + (size_t)BB*TT*HH;
  _Float16* x2hi = aBLo + (size_t)BB*TT*HH;  // N*H
  _Float16* x2lo = x2hi + (size_t)NN*HH;
  _Float16* pHi  = x2lo + (size_t)NN*HH;     // N*H
  _Float16* pLo  = pHi + (size_t)NN*HH;
  _Float16* Whi  = pLo + (size_t)NN*HH;      // 3*384*128
  _Float16* Wlo  = Whi + (size_t)3*G3*HH;
  _Float16* w1th = Wlo + (size_t)3*G3*HH;    // 128*128 each
  _Float16* w1tl = w1th + (size_t)HH*HH;
  _Float16* w2th = w1tl + (size_t)HH*HH;
  _Float16* w2tl = w2th + (size_t)HH*HH;
  int* idx  = (int*)(w2tl + (size_t)HH*HH);  // E*MAXNNZ
  int* cnt  = idx + (size_t)EE*MAXNNZ;       // E
  int* ndeg = cnt + EE;                      // N
  int* nidx = ndeg + NN;                     // N*MAXDEG

  // ---- prep ----
  hipMemsetAsync(ndeg, 0, NN*sizeof(int), stream);
  build_nnz<<<EE, 256, 0, stream>>>(Hb, idx, cnt);
  build_nodelists<<<EE, 128, 0, stream>>>(idx, cnt, ndeg, nidx);
  prep_w<<<(3*G3*HH + 255)/256, 256, 0, stream>>>(Wih, Whi, Wlo, 3*G3*HH);
  prep_wt<<<HH*HH/256, 256, 0, stream>>>(w1, w1th, w1tl);
  prep_wt<<<HH*HH/256, 256, 0, stream>>>(w2, w2th, w2tl);
  prep_split<<<NN*HH/256, 256, 0, stream>>>(poi, pHi, pLo, NN*HH);

  // ---- hypergraph conv phase ----
  mm128_mfma<true><<<NN/32, 256, 0, stream>>>(pHi, pLo, w1th, w1tl, b1, DV2, x1s);
  edge_gather<<<EE, 128, 0, stream>>>(x1s, idx, cnt, invDE, ebuf);
  node_gather<1><<<NN, 128, 0, stream>>>(ebuf, nidx, ndeg, DV2, poi, x2hi, x2lo, (float*)nullptr);
  mm128_mfma<true><<<NN/32, 256, 0, stream>>>(x2hi, x2lo, w2th, w2tl, b2, DV2, x3s);
  edge_gather<<<EE, 128, 0, stream>>>(x3s, idx, cnt, invDE, ebuf);
  node_gather<2><<<NN, 128, 0, stream>>>(ebuf, nidx, ndeg, DV2, (const float*)nullptr,
                                         (_Float16*)nullptr, (_Float16*)nullptr, x4);
  gather_emb<<<BB*TT/2, 256, 0, stream>>>(x4, data, a0Hi, a0Lo);

  // ---- fused 3-layer GRU stack ----
  gru_fused<<<BB/2, 512, 0, stream>>>(Whh, bhh, Whi, Wlo, bih, dlen,
                                      (const float*)nullptr, a0Hi, a0Lo,
                                      aAHi, aALo, aBHi, aBLo, gx, out);
}

// Round 16
// 481.022 us; speedup vs baseline: 3.0460x; 1.1525x over previous
//
#include <hip/hip_runtime.h>

#define NN 8192
#define EE 2048
#define BB 512
#define TT 128
#define HH 128
#define G3 384
#define MAXNNZ 256
#define MAXDEG 96

typedef __attribute__((ext_vector_type(8))) _Float16 f16x8;
typedef __attribute__((ext_vector_type(4))) float f32x4;

__device__ __forceinline__ float sigm(float x){ return 1.0f/(1.0f+__expf(-x)); }
__device__ __forceinline__ float tanhfast(float x){ return 2.0f/(1.0f+__expf(-2.0f*x)) - 1.0f; }

// barrier ordering LDS only; global loads/stores stay in flight.
__device__ __forceinline__ void bar_lds(){
  __builtin_amdgcn_sched_barrier(0);
  asm volatile("s_waitcnt lgkmcnt(0)\n\ts_barrier" ::: "memory");
  __builtin_amdgcn_sched_barrier(0);
}

// ---- build per-edge nonzero index lists (Hbat is exactly binary) ----
__global__ __launch_bounds__(256)
void build_nnz(const float* __restrict__ Hb, int* __restrict__ idx, int* __restrict__ cnt){
  __shared__ int c;
  const int e = blockIdx.x;
  if (threadIdx.x == 0) c = 0;
  __syncthreads();
  const float* row = Hb + (size_t)e * NN;
  for (int n = threadIdx.x; n < NN; n += 256){
    if (row[n] != 0.0f){
      int p = atomicAdd(&c, 1);
      if (p < MAXNNZ) idx[e*MAXNNZ + p] = n;
    }
  }
  __syncthreads();
  if (threadIdx.x == 0) cnt[e] = (c < MAXNNZ ? c : MAXNNZ);
}

// ---- invert edge lists into per-node edge lists ----
__global__ __launch_bounds__(128)
void build_nodelists(const int* __restrict__ idx, const int* __restrict__ cnt,
                     int* __restrict__ ndeg, int* __restrict__ nidx){
  const int e = blockIdx.x;
  const int c = cnt[e];
  for (int k = threadIdx.x; k < c; k += 128){
    int n = idx[e*MAXNNZ + k];
    int p = atomicAdd(&ndeg[n], 1);
    if (p < MAXDEG) nidx[n*MAXDEG + p] = e;
  }
}

// ---- split (16*W) into fp16 hi/lo, row-major passthrough ----
__global__ __launch_bounds__(256)
void prep_w(const float* __restrict__ W, _Float16* __restrict__ whi,
            _Float16* __restrict__ wlo, int n){
  int i = blockIdx.x*256 + threadIdx.x;
  if (i >= n) return;
  float g = W[i] * 16.0f;
  _Float16 h = (_Float16)g;
  whi[i] = h;
  wlo[i] = (_Float16)(g - (float)h);
}

// ---- plain split X into fp16 hi/lo (no scale) ----
__global__ __launch_bounds__(256)
void prep_split(const float* __restrict__ X, _Float16* __restrict__ hi,
                _Float16* __restrict__ lo, int n){
  int i = blockIdx.x*256 + threadIdx.x;
  if (i >= n) return;
  float v = X[i];
  _Float16 h = (_Float16)v;
  hi[i] = h;
  lo[i] = (_Float16)(v - (float)h);
}

// ---- transpose + split (16*W) 128x128: wt[j,k] = 16*W[k,j] ----
__global__ __launch_bounds__(256)
void prep_wt(const float* __restrict__ W, _Float16* __restrict__ wt_hi,
             _Float16* __restrict__ wt_lo){
  int i = blockIdx.x*256 + threadIdx.x;   // 16384 total
  int k = i >> 7, j = i & 127;
  float g = W[i] * 16.0f;
  _Float16 h = (_Float16)g;
  wt_hi[j*HH + k] = h;
  wt_lo[j*HH + k] = (_Float16)(g - (float)h);
}

// ---- conv-phase MFMA GEMM on pre-split A: C[r,j] = rowscale[r]*(A@W + bias) ----
template<bool SCALE>
__global__ __launch_bounds__(256)
void mm128_mfma(const _Float16* __restrict__ Ahi, const _Float16* __restrict__ Alo,
                const _Float16* __restrict__ Bh, const _Float16* __restrict__ Bl,
                const float* __restrict__ bias, const float* __restrict__ rowscale,
                float* __restrict__ C)
{
  const int tid = threadIdx.x;
  const int w = tid >> 6, l = tid & 63;
  const int lm = l & 15, q = l >> 4;
  const int r0 = blockIdx.x * 32;
  const int n0 = w * 32;

  f32x4 acc[2][2];
  #pragma unroll
  for (int m=0;m<2;m++)
    #pragma unroll
    for (int n=0;n<2;n++) acc[m][n] = (f32x4){0.f,0.f,0.f,0.f};

  #pragma unroll 2
  for (int ks = 0; ks < 4; ++ks){
    const int kb = ks*32 + q*8;
    f16x8 ah[2], al[2];
    #pragma unroll
    for (int m=0;m<2;m++){
      const size_t ro = (size_t)(r0 + m*16 + lm)*HH + kb;
      ah[m] = *(const f16x8*)(Ahi + ro);
      al[m] = *(const f16x8*)(Alo + ro);
    }
    #pragma unroll
    for (int n=0;n<2;n++){
      const int j = n0 + n*16 + lm;
      f16x8 bh = *(const f16x8*)(Bh + (size_t)j*HH + kb);
      f16x8 bl = *(const f16x8*)(Bl + (size_t)j*HH + kb);
      #pragma unroll
      for (int m=0;m<2;m++){
        acc[m][n] = __builtin_amdgcn_mfma_f32_16x16x32_f16(ah[m], bh, acc[m][n], 0,0,0);
        acc[m][n] = __builtin_amdgcn_mfma_f32_16x16x32_f16(al[m], bh, acc[m][n], 0,0,0);
        acc[m][n] = __builtin_amdgcn_mfma_f32_16x16x32_f16(ah[m], bl, acc[m][n], 0,0,0);
      }
    }
  }
  #pragma unroll
  for (int n=0;n<2;n++){
    const int j = n0 + n*16 + lm;
    const float bv = bias[j];
    #pragma unroll
    for (int m=0;m<2;m++){
      #pragma unroll
      for (int i=0;i<4;i++){
        int r = r0 + m*16 + q*4 + i;
        float cv = acc[m][n][i]*(1.0f/16.0f) + bv;
        if (SCALE) cv *= rowscale[r];
        C[(size_t)r*HH + j] = cv;
      }
    }
  }
}

// ---- edge gather: Eb[e,:] = invDE[e] * sum_{n in edge e} Xs[n,:] ----
__global__ __launch_bounds__(128)
void edge_gather(const float* __restrict__ Xs, const int* __restrict__ idx,
                 const int* __restrict__ cnt, const float* __restrict__ invDE,
                 float* __restrict__ Eb){
  __shared__ int sidx[MAXNNZ];
  const int e = blockIdx.x, h = threadIdx.x;
  const int c = cnt[e];
  for (int k = h; k < c; k += 128) sidx[k] = idx[e*MAXNNZ + k];
  __syncthreads();
  float acc = 0.0f;
  int k = 0;
  for (; k + 4 <= c; k += 4){
    float a0 = Xs[(size_t)sidx[k+0]*HH + h];
    float a1 = Xs[(size_t)sidx[k+1]*HH + h];
    float a2 = Xs[(size_t)sidx[k+2]*HH + h];
    float a3 = Xs[(size_t)sidx[k+3]*HH + h];
    acc += (a0 + a1) + (a2 + a3);
  }
  for (; k < c; ++k) acc += Xs[(size_t)sidx[k]*HH + h];
  Eb[e*HH + h] = invDE[e] * acc;
}

// ---- node gather: v = DV2[n] * sum_{e ∋ n} Eb[e,:]; MODE1: split(relu(v)+poi), MODE2: fp32 v ----
template<int MODE>
__global__ __launch_bounds__(128)
void node_gather(const float* __restrict__ Eb, const int* __restrict__ nidx,
                 const int* __restrict__ ndeg, const float* __restrict__ DV2,
                 const float* __restrict__ poi, _Float16* __restrict__ ohi,
                 _Float16* __restrict__ olo, float* __restrict__ Xo){
  __shared__ int sidx[MAXDEG];
  const int n = blockIdx.x, h = threadIdx.x;
  int c = ndeg[n]; c = c < MAXDEG ? c : MAXDEG;
  for (int k = h; k < c; k += 128) sidx[k] = nidx[n*MAXDEG + k];
  __syncthreads();
  float acc = 0.0f;
  int k = 0;
  for (; k + 4 <= c; k += 4){
    float a0 = Eb[(size_t)sidx[k+0]*HH + h];
    float a1 = Eb[(size_t)sidx[k+1]*HH + h];
    float a2 = Eb[(size_t)sidx[k+2]*HH + h];
    float a3 = Eb[(size_t)sidx[k+3]*HH + h];
    acc += (a0 + a1) + (a2 + a3);
  }
  for (; k < c; ++k) acc += Eb[(size_t)sidx[k]*HH + h];
  float v = DV2[n] * acc;
  if (MODE == 1){
    float val = fmaxf(v, 0.0f) + poi[(size_t)n*HH + h];
    _Float16 hh = (_Float16)val;
    ohi[(size_t)n*HH + h] = hh;
    olo[(size_t)n*HH + h] = (_Float16)(val - (float)hh);
  } else {
    Xo[(size_t)n*HH + h] = v;
  }
}

// ---- gather emb rows + write fp16 hi/lo split (layer-0 GEMM A operand) ----
__global__ __launch_bounds__(256)
void gather_emb(const float* __restrict__ X, const int* __restrict__ data,
                float* __restrict__ emb, _Float16* __restrict__ aHi,
                _Float16* __restrict__ aLo){
  int r = blockIdx.x*2 + (threadIdx.x >> 7);
  int h = threadIdx.x & 127;
  int n = data[r];
  float v = X[(size_t)n*HH + h];
  size_t o = (size_t)r*HH + h;
  emb[o] = v;
  _Float16 hh = (_Float16)v;
  aHi[o] = hh;
  aLo[o] = (_Float16)(v - (float)hh);
}

// ---- fused 3-layer GRU stack (r11 structure). One block = 2 batches.
// Per layer: gx phase (in-block MFMA GEMM to gxb) -> syncthreads ->
// scan phase: phase A (gh MFMA, 8 waves) / phase B (gates on waves 0-3;
// DEFERRED aOut emission for step t-1 on waves 4-7), 2 lgkm barriers/step.
__global__ __launch_bounds__(512, 1)
void gru_fused(const float* __restrict__ WhhAll, const float* __restrict__ bhhAll,
               const _Float16* __restrict__ WhiAll, const _Float16* __restrict__ WloAll,
               const float* __restrict__ bihAll, const int* __restrict__ lens,
               const float* __restrict__ emb, _Float16* __restrict__ aHi,
               _Float16* __restrict__ aLo, float* __restrict__ gxb,
               float* __restrict__ out)
{
  __shared__ _Float16 hbuf[2][16*HH];   // 8 KB; rows 2..15 stay zero
  __shared__ float ghT[2][392];
  const int tid = threadIdx.x;
  const int w = tid >> 6, lane = tid & 63;
  const int lm = lane & 15, q = lane >> 4;
  const int b0 = blockIdx.x * 2;
  const int n0 = w * 48;                // wave's 48-col slab (x8 waves = 384)

  const int len0 = lens[b0], len1 = lens[b0+1];
  const int lenmax = len0;              // sorted descending
  const int ntl[2] = {(len0+15)>>4, (len1+15)>>4};

  // lower waves (tid<256): gates for (gb,gd). upper waves: aOut for (ub,ud).
  const int gb = (tid >> 7) & 1;
  const int gd = tid & 127;
  const float* gxrow = gxb + (size_t)(b0+gb)*TT*G3;
  const int glen = gb ? len1 : len0;
  const int ub = (tid >> 7) & 1;        // same formula both halves
  const int ud = tid & 127;
  const float* erow2 = emb + (size_t)(b0+ub)*TT*HH + ud;
  const int uoff = (ub*256 + ud*2) ^ (ub << 4);

  #pragma unroll 1
  for (int l = 0; l < 3; ++l){
    const bool fin = (l == 2);
    const _Float16* Whi = WhiAll + (size_t)l*G3*HH;
    const _Float16* Wlo = WloAll + (size_t)l*G3*HH;
    const float* bih = bihAll + l*G3;
    const float* Whh = WhhAll + (size_t)l*G3*HH;
    const float* bhh = bhhAll + l*G3;

    // ---- gx phase: gx[b][t][g] = A @ Wih^T + bih for this block's rows ----
    #pragma unroll 1
    for (int bb = 0; bb < 2; ++bb){
      const int ntb = ntl[bb];
      #pragma unroll 1
      for (int rt = 0; rt < ntb; ++rt){
        f32x4 acc0 = (f32x4){0.f,0.f,0.f,0.f}, acc1 = acc0, acc2 = acc0;
        #pragma unroll
        for (int ks = 0; ks < 4; ++ks){
          const int kb = ks*32 + q*8;
          const size_t ro = ((size_t)(b0+bb)*TT + rt*16 + lm)*HH + kb;
          f16x8 ah = *(const f16x8*)(aHi + ro);
          f16x8 al = *(const f16x8*)(aLo + ro);
          {
            const int g = n0 + lm;
            f16x8 bh = *(const f16x8*)(Whi + (size_t)g*HH + kb);
            f16x8 bl = *(const f16x8*)(Wlo + (size_t)g*HH + kb);
            acc0 = __builtin_amdgcn_mfma_f32_16x16x32_f16(ah, bh, acc0, 0,0,0);
            acc0 = __builtin_amdgcn_mfma_f32_16x16x32_f16(al, bh, acc0, 0,0,0);
            acc0 = __builtin_amdgcn_mfma_f32_16x16x32_f16(ah, bl, acc0, 0,0,0);
          }
          {
            const int g = n0 + 16 + lm;
            f16x8 bh = *(const f16x8*)(Whi + (size_t)g*HH + kb);
            f16x8 bl = *(const f16x8*)(Wlo + (size_t)g*HH + kb);
            acc1 = __builtin_amdgcn_mfma_f32_16x16x32_f16(ah, bh, acc1, 0,0,0);
            acc1 = __builtin_amdgcn_mfma_f32_16x16x32_f16(al, bh, acc1, 0,0,0);
            acc1 = __builtin_amdgcn_mfma_f32_16x16x32_f16(ah, bl, acc1, 0,0,0);
          }
          {
            const int g = n0 + 32 + lm;
            f16x8 bh = *(const f16x8*)(Whi + (size_t)g*HH + kb);
            f16x8 bl = *(const f16x8*)(Wlo + (size_t)g*HH + kb);
            acc2 = __builtin_amdgcn_mfma_f32_16x16x32_f16(ah, bh, acc2, 0,0,0);
            acc2 = __builtin_amdgcn_mfma_f32_16x16x32_f16(al, bh, acc2, 0,0,0);
            acc2 = __builtin_amdgcn_mfma_f32_16x16x32_f16(ah, bl, acc2, 0,0,0);
          }
        }
        float* gout = gxb + ((size_t)(b0+bb)*TT + rt*16)*G3;
        #pragma unroll
        for (int i=0;i<4;i++){
          const int t = q*4 + i;
          gout[(size_t)t*G3 + n0 + lm]      = acc0[i]*(1.0f/16.0f) + bih[n0 + lm];
          gout[(size_t)t*G3 + n0 + 16 + lm] = acc1[i]*(1.0f/16.0f) + bih[n0 + 16 + lm];
          gout[(size_t)t*G3 + n0 + 32 + lm] = acc2[i]*(1.0f/16.0f) + bih[n0 + 32 + lm];
        }
      }
    }

    // ---- load Whh fragments for scan (wave w: cols n0 + {0,16,32} + lm) ----
    f16x8 wf[3][4];
    #pragma unroll
    for (int n=0; n<3; ++n){
      const int col = n0 + n*16 + lm;
      const float* wr = Whh + (size_t)col*HH;
      #pragma unroll
      for (int ks=0; ks<4; ++ks){
        const int kb = ks*32 + q*8;
        float4 f0 = *(const float4*)(wr + kb);
        float4 f1 = *(const float4*)(wr + kb + 4);
        float fv[8] = {f0.x,f0.y,f0.z,f0.w,f1.x,f1.y,f1.z,f1.w};
        union { f16x8 v; _Float16 u[8]; } uu;
        #pragma unroll
        for (int j=0;j<8;j++) uu.u[j] = (_Float16)(fv[j] * 16.0f);
        wf[n][ks] = uu.v;
      }
    }
    const float S = 1.0f/16.0f;
    const float bR = bhh[gd], bZ = bhh[HH+gd], bN = bhh[2*HH+gd];
    _Float16* ahrow2 = aHi + (size_t)(b0+ub)*TT*HH + ud;
    _Float16* alrow2 = aLo + (size_t)(b0+ub)*TT*HH + ud;

    {   // zero both h buffers
      unsigned int* z = (unsigned int*)&hbuf[0][0];
      #pragma unroll 1
      for (int i = tid; i < 2*16*HH/2; i += 512) z[i] = 0u;
    }
    __syncthreads();   // drains gx stores (vmcnt 0) + orders hbuf zero

    // prefetch t = 0
    float xv0=0.f, xv1=0.f, xv2=0.f, hp=0.f, fo=0.f, xe2=0.f;
    if (tid < 256){
      xv0 = gxrow[gd]; xv1 = gxrow[128+gd]; xv2 = gxrow[256+gd];
    } else if (!fin){
      xe2 = erow2[0];
    }

    int cur = 0;
    #pragma unroll 1
    for (int t = 0; t < lenmax; ++t){
      // phase A: MFMA on all 8 waves
      f16x8 av[4];
      #pragma unroll
      for (int ks=0; ks<4; ++ks){
        int off = (lm*256 + ks*64 + q*16) ^ ((lm & 7) << 4);
        av[ks] = *(const f16x8*)((const char*)&hbuf[cur][0] + off);
      }
      // prefetch t+1 gx (in flight across lgkm-only barriers)
      float xn0=0.f, xn1=0.f, xn2=0.f;
      if (tid < 256){
        int tp = (t+1 < lenmax) ? t+1 : t;
        const float* bgx = gxrow + (size_t)tp*G3;
        xn0 = bgx[gd]; xn1 = bgx[128+gd]; xn2 = bgx[256+gd];
      }
      f32x4 a0 = (f32x4){0.f,0.f,0.f,0.f}, a1 = a0, a2 = a0;
      #pragma unroll
      for (int ks=0; ks<4; ++ks){
        a0 = __builtin_amdgcn_mfma_f32_16x16x32_f16(av[ks], wf[0][ks], a0, 0,0,0);
        a1 = __builtin_amdgcn_mfma_f32_16x16x32_f16(av[ks], wf[1][ks], a1, 0,0,0);
        a2 = __builtin_amdgcn_mfma_f32_16x16x32_f16(av[ks], wf[2][ks], a2, 0,0,0);
      }
      if (q == 0){   // rows 0,1 = batches 0,1
        const int c0 = n0 + lm;
        ghT[0][c0]      = a0[0];  ghT[1][c0]      = a0[1];
        ghT[0][c0+16]   = a1[0];  ghT[1][c0+16]   = a1[1];
        ghT[0][c0+32]   = a2[0];  ghT[1][c0+32]   = a2[1];
      }
      bar_lds();

      // phase B: gates on waves 0-3; deferred aOut(t-1) on waves 4-7
      if (tid < 256){
        float gr = ghT[gb][gd], gz = ghT[gb][128+gd], gn = ghT[gb][256+gd];
        float r = sigm(xv0 + gr*S + bR);
        float z = sigm(xv1 + gz*S + bZ);
        float n = tanhfast(xv2 + r*(gn*S + bN));
        float hnew = (1.0f - z)*n + z*hp;
        hp = hnew;
        int off = (gb*256 + gd*2) ^ (gb << 4);
        *(_Float16*)((char*)&hbuf[cur^1][0] + off) = (_Float16)hnew;
        if (fin && t == glen - 1) fo = tanhfast(hnew);
      } else if (!fin && t > 0){
        // h(t-1) lives in hbuf[cur]; emit A row t-1 for next layer
        float hprev = (float)(*(const _Float16*)((const char*)&hbuf[cur][0] + uoff));
        float a = xe2 + fmaxf(hprev, 0.0f);
        _Float16 ah = (_Float16)a;
        ahrow2[(size_t)(t-1)*HH] = ah;
        alrow2[(size_t)(t-1)*HH] = (_Float16)(a - (float)ah);
        xe2 = erow2[(size_t)t*HH];   // emb row t for next emission
      }
      xv0 = xn0; xv1 = xn1; xv2 = xn2;
      bar_lds();
      cur ^= 1;
    }

    if (fin){
      if (tid < 256)
        out[(size_t)(b0+gb)*HH + gd] = fo;
    } else {
      // tail: emit A row lenmax-1 (h is in hbuf[cur] after final flip)
      if (tid >= 256){
        float hprev = (float)(*(const _Float16*)((const char*)&hbuf[cur][0] + uoff));
        float a = xe2 + fmaxf(hprev, 0.0f);
        _Float16 ah = (_Float16)a;
        ahrow2[(size_t)(lenmax-1)*HH] = ah;
        alrow2[(size_t)(lenmax-1)*HH] = (_Float16)(a - (float)ah);
      }
      __syncthreads();   // drain aOut stores before next layer's gx phase
    }
  }
}

extern "C" void kernel_launch(void* const* d_in, const int* in_sizes, int n_in,
                              void* d_out, int out_size, void* d_ws, size_t ws_size,
                              hipStream_t stream)
{
  const float* Hb    = (const float*)d_in[0];
  const float* DV2   = (const float*)d_in[1];
  const float* invDE = (const float*)d_in[2];
  const int*   data  = (const int*)d_in[3];
  const int*   dlen  = (const int*)d_in[4];
  const float* poi   = (const float*)d_in[5];
  const float* w1    = (const float*)d_in[6];
  const float* b1    = (const float*)d_in[7];
  const float* w2    = (const float*)d_in[8];
  const float* b2    = (const float*)d_in[9];
  const float* Wih   = (const float*)d_in[10];
  const float* Whh   = (const float*)d_in[11];
  const float* bih   = (const float*)d_in[12];
  const float* bhh   = (const float*)d_in[13];
  float* out = (float*)d_out;

  float* ws   = (float*)d_ws;
  float* x1s  = ws;                          // N*H f32
  float* x3s  = x1s + (size_t)NN*HH;         // N*H f32
  float* x4   = x3s + (size_t)NN*HH;         // N*H f32
  float* ebuf = x4  + (size_t)NN*HH;         // E*H f32
  float* gx   = ebuf + (size_t)EE*HH;        // B*T*3H f32
  float* emb  = gx  + (size_t)BB*TT*G3;      // B*T*H f32
  _Float16* aHi  = (_Float16*)(emb + (size_t)BB*TT*HH); // B*T*H
  _Float16* aLo  = aHi + (size_t)BB*TT*HH;
  _Float16* x2hi = aLo + (size_t)BB*TT*HH;   // N*H
  _Float16* x2lo = x2hi + (size_t)NN*HH;
  _Float16* pHi  = x2lo + (size_t)NN*HH;     // N*H
  _Float16* pLo  = pHi + (size_t)NN*HH;
  _Float16* Whi  = pLo + (size_t)NN*HH;      // 3*384*128
  _Float16* Wlo  = Whi + (size_t)3*G3*HH;
  _Float16* w1th = Wlo + (size_t)3*G3*HH;    // 128*128 each
  _Float16* w1tl = w1th + (size_t)HH*HH;
  _Float16* w2th = w1tl + (size_t)HH*HH;
  _Float16* w2tl = w2th + (size_t)HH*HH;
  int* idx  = (int*)(w2tl + (size_t)HH*HH);  // E*MAXNNZ
  int* cnt  = idx + (size_t)EE*MAXNNZ;       // E
  int* ndeg = cnt + EE;                      // N
  int* nidx = ndeg + NN;                     // N*MAXDEG

  // ---- prep ----
  hipMemsetAsync(ndeg, 0, NN*sizeof(int), stream);
  build_nnz<<<EE, 256, 0, stream>>>(Hb, idx, cnt);
  build_nodelists<<<EE, 128, 0, stream>>>(idx, cnt, ndeg, nidx);
  prep_w<<<(3*G3*HH + 255)/256, 256, 0, stream>>>(Wih, Whi, Wlo, 3*G3*HH);
  prep_wt<<<HH*HH/256, 256, 0, stream>>>(w1, w1th, w1tl);
  prep_wt<<<HH*HH/256, 256, 0, stream>>>(w2, w2th, w2tl);
  prep_split<<<NN*HH/256, 256, 0, stream>>>(poi, pHi, pLo, NN*HH);

  // ---- hypergraph conv phase ----
  mm128_mfma<true><<<NN/32, 256, 0, stream>>>(pHi, pLo, w1th, w1tl, b1, DV2, x1s);
  edge_gather<<<EE, 128, 0, stream>>>(x1s, idx, cnt, invDE, ebuf);
  node_gather<1><<<NN, 128, 0, stream>>>(ebuf, nidx, ndeg, DV2, poi, x2hi, x2lo, (float*)nullptr);
  mm128_mfma<true><<<NN/32, 256, 0, stream>>>(x2hi, x2lo, w2th, w2tl, b2, DV2, x3s);
  edge_gather<<<EE, 128, 0, stream>>>(x3s, idx, cnt, invDE, ebuf);
  node_gather<2><<<NN, 128, 0, stream>>>(ebuf, nidx, ndeg, DV2, (const float*)nullptr,
                                         (_Float16*)nullptr, (_Float16*)nullptr, x4);
  gather_emb<<<BB*TT/2, 256, 0, stream>>>(x4, data, emb, aHi, aLo);

  // ---- fused 3-layer GRU stack ----
  gru_fused<<<BB/2, 512, 0, stream>>>(Whh, bhh, Whi, Wlo, bih, dlen,
                                      emb, aHi, aLo, gx, out);
}